// Round 5
// baseline (303.633 us; speedup 1.0000x reference)
//
#include <hip/hip_runtime.h>
#include <cstdint>

static constexpr int S = 1024;
static constexpr int T = 32;
static constexpr float L2E  = 1.4426950408889634f;  // log2(e)
static constexpr float LN2f = 0.6931471805599453f;  // ln(2)

typedef __attribute__((ext_vector_type(8)))  short  short8;
typedef __attribute__((ext_vector_type(16))) float  float16;

union Frag { unsigned u[4]; short8 s; };

__global__ void crf_zero(float* ws) {
  ws[0] = 0.0f; ws[1] = 0.0f; ((unsigned*)ws)[2] = 0u;
}

__device__ __forceinline__ float bcast_lane(float v, int k) {
  return __uint_as_float((unsigned)__builtin_amdgcn_readlane((int)__float_as_uint(v), k));
}

// pack two f32 -> bf16x2, elt0 (low) = first arg
__device__ __forceinline__ unsigned pk2(float lo, float hi) {
#if __has_builtin(__builtin_amdgcn_cvt_pk_bf16_f32)
  typedef __attribute__((ext_vector_type(2))) __bf16 bf162_t;
  union { bf162_t v; unsigned u; } r;
  r.v = __builtin_amdgcn_cvt_pk_bf16_f32(lo, hi);
  return r.u;
#else
  unsigned h_ = __float_as_uint(hi), l_ = __float_as_uint(lo);
  return ((h_ + 0x8000u) & 0xFFFF0000u) | ((l_ + 0x8000u) >> 16);
#endif
}

// exchange register halves between lane halves (C-layout -> B-layout fix)
__device__ __forceinline__ void plswap(unsigned& x, unsigned& y, bool hih) {
#if __has_builtin(__builtin_amdgcn_permlane32_swap)
  auto r = __builtin_amdgcn_permlane32_swap((int)x, (int)y, false, false);
  x = (unsigned)r[0]; y = (unsigned)r[1];
#else
  unsigned ex = (unsigned)__shfl_xor((int)x, 32, 64);
  unsigned ey = (unsigned)__shfl_xor((int)y, 32, 64);
  unsigned nx = hih ? ey : x;
  unsigned ny = hih ? y  : ex;
  x = nx; y = ny;
#endif
}

// Block = one batch (512 thr = 8 waves). The active step range (head, tail]
// is split into 8 EQUAL chunks (load balance); wave w folds its chunk into a
// 32x32 matrix via MFMA in the linear 2^x domain (A_j = diag(g_j) P^T, M in
// B-layout, A = P^T constant). Chunk matrices published as packed bf16
// (pad-34 rows). Wave 0 then scans the 8 matrices; numerator fused.
// Last finished block writes the final scalar (no separate fin kernel).
// launch_bounds min-waves = 4: VGPR cap 128 (fold body needs ~52-64; the
// (512,8) variant spilled — 34 MB scratch writes — and was net neutral).
// Occupancy is then LDS-limited: 40448 B * 4 blocks/CU -> 8 waves/SIMD.
__global__ __launch_bounds__(512, 4) void crf_main(
    const float* __restrict__ em, const int* __restrict__ tags,
    const int* __restrict__ mask, const float* __restrict__ startT,
    const float* __restrict__ trans, const float* __restrict__ endT,
    float* __restrict__ ws, float* __restrict__ out, int B)
{
  __shared__ __align__(16) float    s_g[8 * 512];      // 16 KiB: per-wave g staging
  __shared__ __align__(16) unsigned s_mats[8 * 544];   // 17 KiB: bf16 chunk mats, rows pad 34
  __shared__ float s_trans[1024];                      // 4 KiB
  __shared__ short s_tags[1024];                       // 2 KiB
  __shared__ unsigned long long s_mb[17];
  __shared__ int   s_head, s_tail, s_cnt, s_K[8];
  __shared__ float s_num[8];

  const int tid = threadIdx.x;
  const int l   = tid & 63;
  const int wv  = tid >> 6;
  const int b   = blockIdx.x;
  const int n   = l & 31;        // MFMA column / tag index
  const int h   = l >> 5;        // lane half
  const bool hih = (h == 1);

  const float* emb   = em   + (size_t)b * S * T;
  const int*   maskb = mask + (size_t)b * S;
  const int*   tagsb = tags + (size_t)b * S;

  // ---- cooperative staging: tags, trans, mask ballots ----
  for (int i = tid; i < 1024; i += 512) {
    s_tags[i]  = (short)tagsb[i];
    s_trans[i] = trans[i];
  }
  {
    unsigned long long b0 = __ballot(maskb[wv * 128 + l] != 0);
    unsigned long long b1 = __ballot(maskb[wv * 128 + 64 + l] != 0);
    if (l == 0) { s_mb[2 * wv] = b0; s_mb[2 * wv + 1] = b1; }
    if (tid == 0) s_mb[16] = 0ull;
  }

  // ---- A = P^T as bf16 frags (constant; lane: m=n, k=8h+j) ----
  Frag Alo, Ahi;
  #pragma unroll
  for (int p = 0; p < 4; ++p) {
    int k0 = 8 * h + 2 * p;
    Alo.u[p] = pk2(exp2f(trans[(k0 + 0)  * T + n] * L2E),
                   exp2f(trans[(k0 + 1)  * T + n] * L2E));
    Ahi.u[p] = pk2(exp2f(trans[(k0 + 16) * T + n] * L2E),
                   exp2f(trans[(k0 + 17) * T + n] * L2E));
  }
  __syncthreads();

  if (wv == 0) {
    int first = 0x7fffffff, last = -1, pc = 0;
    if (l < 16) {
      unsigned long long w = s_mb[l];
      if (w) {
        first = 64 * l + (int)__builtin_ctzll(w);
        last  = 64 * l + 63 - (int)__builtin_clzll(w);
        pc    = (int)__builtin_popcountll(w);
      }
    }
    #pragma unroll
    for (int d = 1; d < 64; d <<= 1) {
      first = min(first, __shfl_xor(first, d));
      last  = max(last,  __shfl_xor(last,  d));
      pc   += __shfl_xor(pc, d);
    }
    if (l == 0) { s_head = first; s_tail = last; s_cnt = pc; }
  }
  __syncthreads();
  const int cnt  = s_cnt;
  const int head = (cnt > 0) ? s_head : 0;
  const int tail = (cnt > 0) ? s_tail : 0;

  // ---- equal-split chunk for this wave ----
  const int span = tail - head;             // # steps to fold (0 if single)
  const int Lc   = (span + 7) >> 3;
  const int c0   = head + 1 + wv * Lc;
  const int c1   = min(c0 + Lc, tail + 1);

  float* sgw = s_g + wv * 512;
  Frag Blo, Bhi;                            // running M in B-layout, init = I
  #pragma unroll
  for (int p = 0; p < 4; ++p) {
    int k0 = 8 * h + 2 * p;
    Blo.u[p] = ((k0 == n)      ? 0x3F80u : 0u) | ((k0 + 1  == n) ? 0x3F800000u : 0u);
    Bhi.u[p] = ((k0 + 16 == n) ? 0x3F80u : 0u) | ((k0 + 17 == n) ? 0x3F800000u : 0u);
  }
  int   Kacc  = 0;
  float numer = 0.0f;

#define FOLD(JJ, RSC) do {                                                   \
    const float* gr = sgw + (JJ) * T + 4 * h;                                \
    float4 ga = *(const float4*)(gr);                                        \
    float4 gb = *(const float4*)(gr + 8);                                    \
    float4 gc = *(const float4*)(gr + 16);                                   \
    float4 gd = *(const float4*)(gr + 24);                                   \
    float16 D = {0,0,0,0,0,0,0,0,0,0,0,0,0,0,0,0};                           \
    D = __builtin_amdgcn_mfma_f32_32x32x16_bf16(Alo.s, Blo.s, D, 0, 0, 0);   \
    D = __builtin_amdgcn_mfma_f32_32x32x16_bf16(Ahi.s, Bhi.s, D, 0, 0, 0);   \
    D[0]  *= ga.x; D[1]  *= ga.y; D[2]  *= ga.z; D[3]  *= ga.w;              \
    D[4]  *= gb.x; D[5]  *= gb.y; D[6]  *= gb.z; D[7]  *= gb.w;              \
    D[8]  *= gc.x; D[9]  *= gc.y; D[10] *= gc.z; D[11] *= gc.w;              \
    D[12] *= gd.x; D[13] *= gd.y; D[14] *= gd.z; D[15] *= gd.w;              \
    if (RSC) {                                                               \
      float mx = fmaxf(fmaxf(fmaxf(D[0], D[1]), fmaxf(D[2], D[3])),          \
                       fmaxf(fmaxf(D[4], D[5]), fmaxf(D[6], D[7])));         \
      mx = fmaxf(mx, fmaxf(fmaxf(fmaxf(D[8], D[9]),  fmaxf(D[10], D[11])),   \
                           fmaxf(fmaxf(D[12], D[13]), fmaxf(D[14], D[15]))));\
      mx = fmaxf(mx, __shfl_xor(mx, 1));  mx = fmaxf(mx, __shfl_xor(mx, 2)); \
      mx = fmaxf(mx, __shfl_xor(mx, 4));  mx = fmaxf(mx, __shfl_xor(mx, 8)); \
      mx = fmaxf(mx, __shfl_xor(mx, 16)); mx = fmaxf(mx, __shfl_xor(mx, 32));\
      int E = (int)((__float_as_uint(mx) >> 23) & 0xffu);                    \
      float sc = __uint_as_float((unsigned)(254 - E) << 23);                 \
      Kacc += E - 127;                                                       \
      _Pragma("unroll")                                                      \
      for (int q_ = 0; q_ < 16; ++q_) D[q_] *= sc;                           \
    }                                                                        \
    unsigned u0 = pk2(D[0],  D[1]),  u1 = pk2(D[2],  D[3]);                  \
    unsigned u2 = pk2(D[4],  D[5]),  u3 = pk2(D[6],  D[7]);                  \
    unsigned u4 = pk2(D[8],  D[9]),  u5 = pk2(D[10], D[11]);                 \
    unsigned u6 = pk2(D[12], D[13]), u7 = pk2(D[14], D[15]);                 \
    plswap(u0, u2, hih); plswap(u1, u3, hih);                                \
    plswap(u4, u6, hih); plswap(u5, u7, hih);                                \
    Blo.u[0] = u0; Blo.u[1] = u1; Blo.u[2] = u2; Blo.u[3] = u3;              \
    Bhi.u[0] = u4; Bhi.u[1] = u5; Bhi.u[2] = u6; Bhi.u[3] = u7;              \
  } while (0)

  for (int j0 = c0; j0 < c1; j0 += 16) {
    const int ns = min(16, c1 - j0);
    // 16-bit applied-mask at arbitrary offset j0 (funnel over ballot words)
    const int w = j0 >> 6, o = j0 & 63;
    unsigned long long bits = s_mb[w] >> o;
    if (o) bits |= s_mb[w + 1] << (64 - o);
    unsigned eff = (unsigned)(bits & 0xFFFFull) & (unsigned)((1u << ns) - 1u);

    // stage em -> g = 2^(em*log2e) (rows clamped to stay in-bounds)
    {
      const int i0 = l, i1 = l + 64;
      const int r0 = min(j0 + (i0 >> 3), S - 1), q0 = i0 & 7;
      const int r1 = min(j0 + (i1 >> 3), S - 1), q1 = i1 & 7;
      float4 v0 = ((const float4*)(emb + (size_t)r0 * T))[q0];
      float4 v1 = ((const float4*)(emb + (size_t)r1 * T))[q1];
      v0.x = exp2f(v0.x * L2E); v0.y = exp2f(v0.y * L2E);
      v0.z = exp2f(v0.z * L2E); v0.w = exp2f(v0.w * L2E);
      v1.x = exp2f(v1.x * L2E); v1.y = exp2f(v1.y * L2E);
      v1.z = exp2f(v1.z * L2E); v1.w = exp2f(v1.w * L2E);
      ((float4*)sgw)[i0] = v0; ((float4*)sgw)[i1] = v1;
    }

    // numerator: lanes 0..ns-1 take one step each (em recovered from g)
    if (l < ns && ((eff >> l) & 1u)) {
      int j  = j0 + l;
      int tg = (int)s_tags[j], tp = (int)s_tags[j - 1];
      numer += s_trans[tp * T + tg] + log2f(sgw[l * T + tg]) * LN2f;
    }

    if (eff == 0xFFFFu) {
      #pragma unroll
      for (int jj = 0; jj < 16; ++jj) FOLD(jj, ((jj & 7) == 7));
    } else {
      for (int jj = 0; jj < ns; ++jj)
        if ((eff >> jj) & 1u) FOLD(jj, true);
    }
  }
#undef FOLD

  // ---- publish chunk matrix (packed bf16, row-pair words, pad 34) ----
  {
    unsigned* mw = s_mats + wv * 544;
    #pragma unroll
    for (int p = 0; p < 4; ++p) {
      mw[(4 * h + p)     * 34 + n] = Blo.u[p];
      mw[(4 * h + p + 8) * 34 + n] = Bhi.u[p];
    }
  }
  #pragma unroll
  for (int d = 1; d < 64; d <<= 1) numer += __shfl_xor(numer, d);
  if (l == 0) { s_num[wv] = numer; s_K[wv] = Kacc; }
  __syncthreads();

  // ---- phase 2: wave 0 scans the 8 chunk matrices ----
  if (wv == 0) {
    const int t = n;
    const float em0 = emb[head * T + t];
    float sc0 = (startT[t] + em0) * L2E;
    float m0 = sc0;
    #pragma unroll
    for (int d = 1; d < 32; d <<= 1) m0 = fmaxf(m0, __shfl_xor(m0, d));
    float e = exp2f(sc0 - m0);
    float Mtot = m0;

    const unsigned sh = (t & 1) ? 0u : 16u;   // select row-half of packed word
    for (int c = 0; c < 8; ++c) {
      const unsigned* mw = s_mats + c * 544 + (t >> 1) * 34;
      float acc = 0.0f;
      #pragma unroll
      for (int q2 = 0; q2 < 16; ++q2) {
        uint2 w2 = *(const uint2*)(mw + 2 * q2);
        float vlo = __uint_as_float((w2.x << sh) & 0xFFFF0000u);
        float vhi = __uint_as_float((w2.y << sh) & 0xFFFF0000u);
        acc = fmaf(vlo, bcast_lane(e, 2 * q2), acc);
        acc = fmaf(vhi, bcast_lane(e, 2 * q2 + 1), acc);
      }
      e = acc;
      Mtot += (float)s_K[c];
      float mx = e;
      #pragma unroll
      for (int d = 1; d < 32; d <<= 1) mx = fmaxf(mx, __shfl_xor(mx, d));
      int E = (int)((__float_as_uint(mx) >> 23) & 0xffu);
      e *= __uint_as_float((unsigned)(254 - E) << 23);
      Mtot += (float)(E - 127);
    }

    float fv = e * exp2f(endT[t] * L2E);
    #pragma unroll
    for (int d = 1; d < 32; d <<= 1) fv += __shfl_xor(fv, d);
    float denom = (Mtot + log2f(fv)) * LN2f;

    if (l == 0) {
      if (cnt > 0) {
        float ntot = 0.0f;
        for (int wq = 0; wq < 8; ++wq) ntot += s_num[wq];
        int th = (int)s_tags[head], tt = (int)s_tags[tail];
        ntot += startT[th] + bcast_lane(em0, th) + endT[tt];
        atomicAdd(&ws[0], (denom - ntot) / ((float)cnt + 1e-6f));
        atomicAdd(&ws[1], 1.0f);
      }
      __threadfence();
      unsigned done = atomicAdd((unsigned*)ws + 2, 1u);
      if (done == (unsigned)(B - 1)) {
        __threadfence();
        out[0] = ws[0] / (ws[1] + 1e-6f);
      }
    }
  }
}

extern "C" void kernel_launch(void* const* d_in, const int* in_sizes, int n_in,
                              void* d_out, int out_size, void* d_ws, size_t ws_size,
                              hipStream_t stream) {
  const float* em     = (const float*)d_in[0];
  const int*   tags   = (const int*)d_in[1];
  const int*   mask   = (const int*)d_in[2];
  const float* startT = (const float*)d_in[3];
  const float* trans  = (const float*)d_in[4];
  const float* endT   = (const float*)d_in[5];
  float* out = (float*)d_out;
  float* ws  = (float*)d_ws;

  const int B = in_sizes[0] / (S * T);

  crf_zero<<<1, 1, 0, stream>>>(ws);
  crf_main<<<B, 512, 0, stream>>>(em, tags, mask, startT, trans, endT, ws, out, B);
}

// Round 6
// 283.323 us; speedup vs baseline: 1.0717x; 1.0717x over previous
//
#include <hip/hip_runtime.h>
#include <cstdint>

static constexpr int S = 1024;
static constexpr int T = 32;
static constexpr float L2E  = 1.4426950408889634f;  // log2(e)
static constexpr float LN2f = 0.6931471805599453f;  // ln(2)

typedef __attribute__((ext_vector_type(8)))  short  short8;
typedef __attribute__((ext_vector_type(16))) float  float16;

union Frag { unsigned u[4]; short8 s; };

__global__ void crf_zero(float* ws) {
  ws[0] = 0.0f; ws[1] = 0.0f; ((unsigned*)ws)[2] = 0u;
}

__device__ __forceinline__ float bcast_lane(float v, int k) {
  return __uint_as_float((unsigned)__builtin_amdgcn_readlane((int)__float_as_uint(v), k));
}

// rounded pack two f32 -> bf16x2 (lo = first arg). Cold paths only.
__device__ __forceinline__ unsigned pk2r(float lo, float hi) {
#if __has_builtin(__builtin_amdgcn_cvt_pk_bf16_f32)
  typedef __attribute__((ext_vector_type(2))) __bf16 bf162_t;
  union { bf162_t v; unsigned u; } r;
  r.v = __builtin_amdgcn_cvt_pk_bf16_f32(lo, hi);
  return r.u;
#else
  unsigned h_ = __float_as_uint(hi), l_ = __float_as_uint(lo);
  return ((h_ + 0x8000u) & 0xFFFF0000u) | ((l_ + 0x8000u) >> 16);
#endif
}

// fast pack (hot path): 1-op v_perm byte-select (truncation; bias << threshold)
__device__ __forceinline__ unsigned pk2f(float lo, float hi) {
#if __has_builtin(__builtin_amdgcn_cvt_pk_bf16_f32)
  return pk2r(lo, hi);
#else
  return __builtin_amdgcn_perm(__float_as_uint(hi), __float_as_uint(lo), 0x07060302u);
#endif
}

__device__ __forceinline__ float lo16(unsigned w) { return __uint_as_float(w << 16); }
__device__ __forceinline__ float hi16(unsigned w) { return __uint_as_float(w & 0xFFFF0000u); }

// sigma: fixed row permutation mapping MFMA C-layout row slots onto B-operand
// row slots (swaps 4-blocks 1<->2 within each 16): slot k of the B operand is
// fed matrix row sigma(k). With A pre-permuted (A'[n][k] = P^T[n][sigma(k)])
// the product is exact and D's packed pairs ARE the next B - no lane swap.
__device__ __forceinline__ int sig(int k) {
  int g2 = (k >> 2) & 3;
  if (g2 == 1) g2 = 2; else if (g2 == 2) g2 = 1;
  return (k & ~12) | (g2 << 2);
}

// Block = one batch (512 thr = 8 waves). Active range (head, tail] split into
// 8 equal chunks; wave w folds its chunk into a 32x32 matrix via MFMA in the
// linear 2^x domain (M <- diag(g_j) P^T M). g staged as packed bf16 pairs
// (4x ds_read_b64 broadcast per fold). Wave 0 scans the 8 chunk matrices.
__global__ __launch_bounds__(512, 4) void crf_main(
    const float* __restrict__ em, const int* __restrict__ tags,
    const int* __restrict__ mask, const float* __restrict__ startT,
    const float* __restrict__ trans, const float* __restrict__ endT,
    float* __restrict__ ws, float* __restrict__ out, int B)
{
  __shared__ __align__(16) unsigned s_g16[8 * 256];    // 8 KiB: bf16 g staging
  __shared__ __align__(16) unsigned s_mats[8 * 544];   // 17 KiB: bf16 chunk mats, rows pad 34
  __shared__ float s_trans[1024];                      // 4 KiB
  __shared__ short s_tags[1024];                       // 2 KiB
  __shared__ unsigned long long s_mb[17];
  __shared__ int   s_head, s_tail, s_cnt, s_K[8];
  __shared__ float s_num[8];

  const int tid = threadIdx.x;
  const int l   = tid & 63;
  const int wv  = tid >> 6;
  const int b   = blockIdx.x;
  const int n   = l & 31;        // MFMA column / tag index
  const int h   = l >> 5;        // lane half

  const float* emb   = em   + (size_t)b * S * T;
  const int*   maskb = mask + (size_t)b * S;
  const int*   tagsb = tags + (size_t)b * S;

  // ---- cooperative staging: tags, trans, mask ballots ----
  for (int i = tid; i < 1024; i += 512) {
    s_tags[i]  = (short)tagsb[i];
    s_trans[i] = trans[i];
  }
  {
    unsigned long long b0 = __ballot(maskb[wv * 128 + l] != 0);
    unsigned long long b1 = __ballot(maskb[wv * 128 + 64 + l] != 0);
    if (l == 0) { s_mb[2 * wv] = b0; s_mb[2 * wv + 1] = b1; }
    if (tid == 0) s_mb[16] = 0ull;
  }

  // ---- A' = sigma-permuted P^T as bf16 frags (lane: m=n, k-slot=8h+2p+par) ----
  Frag Alo, Ahi;
  #pragma unroll
  for (int p = 0; p < 4; ++p) {
    int k0 = 8 * h + 2 * p;
    Alo.u[p] = pk2r(exp2f(trans[sig(k0 + 0)      * T + n] * L2E),
                    exp2f(trans[sig(k0 + 1)      * T + n] * L2E));
    Ahi.u[p] = pk2r(exp2f(trans[sig(16 + k0 + 0) * T + n] * L2E),
                    exp2f(trans[sig(16 + k0 + 1) * T + n] * L2E));
  }
  __syncthreads();

  if (wv == 0) {
    int first = 0x7fffffff, last = -1, pc = 0;
    if (l < 16) {
      unsigned long long w = s_mb[l];
      if (w) {
        first = 64 * l + (int)__builtin_ctzll(w);
        last  = 64 * l + 63 - (int)__builtin_clzll(w);
        pc    = (int)__builtin_popcountll(w);
      }
    }
    #pragma unroll
    for (int d = 1; d < 64; d <<= 1) {
      first = min(first, __shfl_xor(first, d));
      last  = max(last,  __shfl_xor(last,  d));
      pc   += __shfl_xor(pc, d);
    }
    if (l == 0) { s_head = first; s_tail = last; s_cnt = pc; }
  }
  __syncthreads();
  const int cnt  = s_cnt;
  const int head = (cnt > 0) ? s_head : 0;
  const int tail = (cnt > 0) ? s_tail : 0;

  // ---- equal-split chunk for this wave ----
  const int span = tail - head;
  const int Lc   = (span + 7) >> 3;
  const int c0   = head + 1 + wv * Lc;
  const int c1   = min(c0 + Lc, tail + 1);

  unsigned* sgw16 = s_g16 + wv * 256;
  Frag Blo, Bhi;                    // running M in sigma-storage, init = I
  #pragma unroll
  for (int p = 0; p < 4; ++p) {
    int k0 = 8 * h + 2 * p;
    Blo.u[p] = ((sig(k0) == n)          ? 0x3F80u : 0u) |
               ((sig(k0 + 1) == n)      ? 0x3F800000u : 0u);
    Bhi.u[p] = ((sig(16 + k0) == n)     ? 0x3F80u : 0u) |
               ((sig(16 + k0 + 1) == n) ? 0x3F800000u : 0u);
  }
  int   Kacc  = 0;
  float numer = 0.0f;

#define FOLD(JJ, RSC) do {                                                   \
    const uint2* gw = (const uint2*)(sgw16 + (JJ) * 16);                     \
    uint2 wa = gw[h], wb = gw[h + 2], wc = gw[h + 4], wd = gw[h + 6];        \
    float16 D = {0,0,0,0,0,0,0,0,0,0,0,0,0,0,0,0};                           \
    D = __builtin_amdgcn_mfma_f32_32x32x16_bf16(Alo.s, Blo.s, D, 0, 0, 0);   \
    D = __builtin_amdgcn_mfma_f32_32x32x16_bf16(Ahi.s, Bhi.s, D, 0, 0, 0);   \
    D[0]  *= lo16(wa.x); D[1]  *= hi16(wa.x);                                \
    D[2]  *= lo16(wa.y); D[3]  *= hi16(wa.y);                                \
    D[4]  *= lo16(wb.x); D[5]  *= hi16(wb.x);                                \
    D[6]  *= lo16(wb.y); D[7]  *= hi16(wb.y);                                \
    D[8]  *= lo16(wc.x); D[9]  *= hi16(wc.x);                                \
    D[10] *= lo16(wc.y); D[11] *= hi16(wc.y);                                \
    D[12] *= lo16(wd.x); D[13] *= hi16(wd.x);                                \
    D[14] *= lo16(wd.y); D[15] *= hi16(wd.y);                                \
    if (RSC) {                                                               \
      float mx = fmaxf(fmaxf(fmaxf(D[0], D[1]), fmaxf(D[2], D[3])),          \
                       fmaxf(fmaxf(D[4], D[5]), fmaxf(D[6], D[7])));         \
      mx = fmaxf(mx, fmaxf(fmaxf(fmaxf(D[8], D[9]),  fmaxf(D[10], D[11])),   \
                           fmaxf(fmaxf(D[12], D[13]), fmaxf(D[14], D[15]))));\
      mx = fmaxf(mx, __shfl_xor(mx, 1));  mx = fmaxf(mx, __shfl_xor(mx, 2)); \
      mx = fmaxf(mx, __shfl_xor(mx, 4));  mx = fmaxf(mx, __shfl_xor(mx, 8)); \
      mx = fmaxf(mx, __shfl_xor(mx, 16)); mx = fmaxf(mx, __shfl_xor(mx, 32));\
      int E = (int)((__float_as_uint(mx) >> 23) & 0xffu);                    \
      float sc = __uint_as_float((unsigned)(254 - E) << 23);                 \
      Kacc += E - 127;                                                       \
      _Pragma("unroll")                                                      \
      for (int q_ = 0; q_ < 16; ++q_) D[q_] *= sc;                           \
    }                                                                        \
    Blo.u[0] = pk2f(D[0],  D[1]);  Blo.u[1] = pk2f(D[2],  D[3]);             \
    Blo.u[2] = pk2f(D[4],  D[5]);  Blo.u[3] = pk2f(D[6],  D[7]);             \
    Bhi.u[0] = pk2f(D[8],  D[9]);  Bhi.u[1] = pk2f(D[10], D[11]);            \
    Bhi.u[2] = pk2f(D[12], D[13]); Bhi.u[3] = pk2f(D[14], D[15]);            \
  } while (0)

  for (int j0 = c0; j0 < c1; j0 += 16) {
    const int ns = min(16, c1 - j0);
    // 16-bit applied-mask at arbitrary offset j0 (funnel over ballot words)
    const int w = j0 >> 6, o = j0 & 63;
    unsigned long long bits = s_mb[w] >> o;
    if (o) bits |= s_mb[w + 1] << (64 - o);
    unsigned eff = (unsigned)(bits & 0xFFFFull) & (unsigned)((1u << ns) - 1u);

    // stage em -> g = 2^(em*log2e), packed bf16 pairs [step][tagpair]
    {
      const int i0 = l, i1 = l + 64;
      const int r0 = min(j0 + (i0 >> 3), S - 1), q0 = i0 & 7;
      const int r1 = min(j0 + (i1 >> 3), S - 1), q1 = i1 & 7;
      float4 v0 = ((const float4*)(emb + (size_t)r0 * T))[q0];
      float4 v1 = ((const float4*)(emb + (size_t)r1 * T))[q1];
      uint2 p0 = make_uint2(pk2r(exp2f(v0.x * L2E), exp2f(v0.y * L2E)),
                            pk2r(exp2f(v0.z * L2E), exp2f(v0.w * L2E)));
      uint2 p1 = make_uint2(pk2r(exp2f(v1.x * L2E), exp2f(v1.y * L2E)),
                            pk2r(exp2f(v1.z * L2E), exp2f(v1.w * L2E)));
      ((uint2*)sgw16)[i0] = p0; ((uint2*)sgw16)[i1] = p1;
    }

    // numerator: lanes 0..ns-1 take one step each (em recovered from bf16 g)
    if (l < ns && ((eff >> l) & 1u)) {
      int j  = j0 + l;
      int tg = (int)s_tags[j], tp = (int)s_tags[j - 1];
      unsigned gword = sgw16[l * 16 + (tg >> 1)];
      float gval = (tg & 1) ? hi16(gword) : lo16(gword);
      numer += s_trans[tp * T + tg] + log2f(gval) * LN2f;
    }

    if (eff == 0xFFFFu) {
      #pragma unroll
      for (int jj = 0; jj < 16; ++jj) FOLD(jj, ((jj & 7) == 7));
    } else {
      for (int jj = 0; jj < ns; ++jj)
        if ((eff >> jj) & 1u) FOLD(jj, true);
    }
  }
#undef FOLD

  // ---- publish chunk matrix (packed bf16 row pairs, sigma-unscrambled) ----
  {
    unsigned* mw = s_mats + wv * 544;
    #pragma unroll
    for (int p = 0; p < 4; ++p) {
      mw[(sig(8 * h + 2 * p)      >> 1) * 34 + n] = Blo.u[p];
      mw[(sig(16 + 8 * h + 2 * p) >> 1) * 34 + n] = Bhi.u[p];
    }
  }
  #pragma unroll
  for (int d = 1; d < 64; d <<= 1) numer += __shfl_xor(numer, d);
  if (l == 0) { s_num[wv] = numer; s_K[wv] = Kacc; }
  __syncthreads();

  // ---- phase 2: wave 0 scans the 8 chunk matrices ----
  if (wv == 0) {
    const int t = n;
    const float em0 = emb[head * T + t];
    float sc0 = (startT[t] + em0) * L2E;
    float m0 = sc0;
    #pragma unroll
    for (int d = 1; d < 32; d <<= 1) m0 = fmaxf(m0, __shfl_xor(m0, d));
    float e = exp2f(sc0 - m0);
    float Mtot = m0;

    const unsigned sh = (t & 1) ? 0u : 16u;   // select row-half of packed word
    for (int c = 0; c < 8; ++c) {
      const unsigned* mw = s_mats + c * 544 + (t >> 1) * 34;
      float acc = 0.0f;
      #pragma unroll
      for (int q2 = 0; q2 < 16; ++q2) {
        uint2 w2 = *(const uint2*)(mw + 2 * q2);
        float vlo = __uint_as_float((w2.x << sh) & 0xFFFF0000u);
        float vhi = __uint_as_float((w2.y << sh) & 0xFFFF0000u);
        acc = fmaf(vlo, bcast_lane(e, 2 * q2), acc);
        acc = fmaf(vhi, bcast_lane(e, 2 * q2 + 1), acc);
      }
      e = acc;
      Mtot += (float)s_K[c];
      float mx = e;
      #pragma unroll
      for (int d = 1; d < 32; d <<= 1) mx = fmaxf(mx, __shfl_xor(mx, d));
      int E = (int)((__float_as_uint(mx) >> 23) & 0xffu);
      e *= __uint_as_float((unsigned)(254 - E) << 23);
      Mtot += (float)(E - 127);
    }

    float fv = e * exp2f(endT[t] * L2E);
    #pragma unroll
    for (int d = 1; d < 32; d <<= 1) fv += __shfl_xor(fv, d);
    float denom = (Mtot + log2f(fv)) * LN2f;

    if (l == 0) {
      if (cnt > 0) {
        float ntot = 0.0f;
        for (int wq = 0; wq < 8; ++wq) ntot += s_num[wq];
        int th = (int)s_tags[head], tt = (int)s_tags[tail];
        ntot += startT[th] + bcast_lane(em0, th) + endT[tt];
        atomicAdd(&ws[0], (denom - ntot) / ((float)cnt + 1e-6f));
        atomicAdd(&ws[1], 1.0f);
      }
      __threadfence();
      unsigned done = atomicAdd((unsigned*)ws + 2, 1u);
      if (done == (unsigned)(B - 1)) {
        __threadfence();
        out[0] = ws[0] / (ws[1] + 1e-6f);
      }
    }
  }
}

extern "C" void kernel_launch(void* const* d_in, const int* in_sizes, int n_in,
                              void* d_out, int out_size, void* d_ws, size_t ws_size,
                              hipStream_t stream) {
  const float* em     = (const float*)d_in[0];
  const int*   tags   = (const int*)d_in[1];
  const int*   mask   = (const int*)d_in[2];
  const float* startT = (const float*)d_in[3];
  const float* trans  = (const float*)d_in[4];
  const float* endT   = (const float*)d_in[5];
  float* out = (float*)d_out;
  float* ws  = (float*)d_ws;

  const int B = in_sizes[0] / (S * T);

  crf_zero<<<1, 1, 0, stream>>>(ws);
  crf_main<<<B, 512, 0, stream>>>(em, tags, mask, startT, trans, endT, ws, out, B);
}